// Round 13
// baseline (428.591 us; speedup 1.0000x reference)
//
#include <hip/hip_runtime.h>
#include <math.h>

#define BB 8
#define NN 10000
#define EE 320000
#define NCHUNK 128
#define CHSZ (EE / NCHUNK)   // 2500
#define LOG2E 1.44269504088896340736f

// ---- ws layout (float offsets) ----
#define OFF_MM   0           // 16: {min0,min1, L2E/(max0-min0), L2E/(max1-min1)}
#define PK_W2P   16          // 352 half2 (bit-stored as float)
#define PK_WNP   368         // 176 half2
#define PK_W1S   544         // 32 f: W1 row34 * L2E
#define PK_B1S   576         // 32 f: b1 * L2E
#define PK_B2S   608         // 22 f: b2 * L2E
#define OFF_WIND 640         // 2*B*N: (speed*cos, speed*sin)
#define OFF_ECS  160640      // 2*E: (cos(city)/dist, sin(city)/dist)
#define OFF_PRE1 800640      // 32*B*N (prescaled by L2E)
#define OFF_PRE2 3360640     // 32*B*N (prescaled by L2E)
#define OFF_OFFP 5920640     // 2*(N+1) uint
#define OFF_TOT  5940642     // 2*N uint
#define OFF_MMP  5960642     // NCHUNK*4 floats
#define OFF_CNTC 5961154     // 2*NCHUNK*N uint
#define OFF_LST  8521154     // 2*E uint
#define OFF_G    9161168     // nb*E*16 floats (16-aligned)

typedef _Float16 half2_t __attribute__((ext_vector_type(2)));
typedef __fp16 fp16v2_t __attribute__((ext_vector_type(2)));

__device__ __forceinline__ float rcpf(float x) {
#if __has_builtin(__builtin_amdgcn_rcpf)
    return __builtin_amdgcn_rcpf(x);
#else
    return __fdividef(1.0f, x);
#endif
}

__device__ __forceinline__ half2_t pkh2(float a, float b) {
#if __has_builtin(__builtin_amdgcn_cvt_pkrtz)
    // cvt_pkrtz returns __fp16 v2 on this toolchain; bit-identical to _Float16 v2
    union { fp16v2_t t; half2_t h; } u;
    u.t = __builtin_amdgcn_cvt_pkrtz(a, b);
    return u.h;
#else
    half2_t r; r.x = (_Float16)a; r.y = (_Float16)b; return r;
#endif
}

__device__ __forceinline__ float fdot2(half2_t a, half2_t b, float c) {
#if __has_builtin(__builtin_amdgcn_fdot2)
    return __builtin_amdgcn_fdot2(a, b, c, false);
#else
    return (float)a.x * (float)b.x + (float)a.y * (float)b.y + c;
#endif
}

// sigmoid with pre-scaled argument: x' = x*log2(e); sig = 1/(1+2^-x')
__device__ __forceinline__ float sig2(float xs) {
    return rcpf(1.0f + exp2f(-xs));
}

__device__ __forceinline__ float sigmf(float x) {
    return __fdividef(1.0f, 1.0f + __expf(-x));
}

union h2f { half2_t h; float f; };

// ---------------- pack: f16 weights (L2E-prescaled where they feed sigmoid) ----
__global__ __launch_bounds__(512) void pack_kernel(const float* __restrict__ W1,
                                                   const float* __restrict__ b1,
                                                   const float* __restrict__ W2,
                                                   const float* __restrict__ b2,
                                                   const float* __restrict__ Wn,
                                                   float* __restrict__ ws) {
    int t = threadIdx.x;
    if (t < 352) {            // W2p[j2*22+k] = (W2[2j2][k], W2[2j2+1][k]) * L2E
        int j2 = t / 22, k = t % 22;
        h2f u; u.h = pkh2(W2[(2 * j2) * 22 + k] * LOG2E, W2[(2 * j2 + 1) * 22 + k] * LOG2E);
        ws[PK_W2P + t] = u.f;
    }
    if (t < 176) {            // Wnp[k2*16+i] = (Wn[2k2][i], Wn[2k2+1][i])  (unscaled)
        int k2 = t / 16, i = t % 16;
        h2f u; u.h = pkh2(Wn[(2 * k2) * 16 + i], Wn[(2 * k2 + 1) * 16 + i]);
        ws[PK_WNP + t] = u.f;
    }
    if (t < 32) {
        ws[PK_W1S + t] = W1[34 * 32 + t] * LOG2E;
        ws[PK_B1S + t] = b1[t] * LOG2E;
    }
    if (t < 22) ws[PK_B2S + t] = b2[t] * LOG2E;
}

// ---------------- CSR build (r9-validated, zero global atomics) ----------------
__global__ __launch_bounds__(256) void count_kernel(const int* __restrict__ ei,
                                                    const float* __restrict__ ea,
                                                    unsigned* __restrict__ cntc,
                                                    float* __restrict__ mmpart) {
    __shared__ unsigned hist[NN];
    __shared__ float mred[4][4];
    const int c = blockIdx.x, a = blockIdx.y, tid = threadIdx.x;
    for (int i = tid; i < NN; i += 256) hist[i] = 0u;
    __syncthreads();
    const int e0 = c * CHSZ;
    float n0 = 3.4e38f, n1 = 3.4e38f, x0 = 0.f, x1 = 0.f;
    for (int k = tid; k < CHSZ; k += 256) {
        int v = ei[(size_t)a * EE + e0 + k];
        atomicAdd(&hist[v], 1u);
        if (a == 0) {
            float2 av = ((const float2*)ea)[e0 + k];
            n0 = fminf(n0, av.x); x0 = fmaxf(x0, av.x);
            n1 = fminf(n1, av.y); x1 = fmaxf(x1, av.y);
        }
    }
    __syncthreads();
    unsigned* dst = cntc + ((size_t)a * NCHUNK + c) * NN;
    for (int i = tid; i < NN; i += 256) dst[i] = hist[i];
    if (a == 0) {
        #pragma unroll
        for (int off = 32; off >= 1; off >>= 1) {
            n0 = fminf(n0, __shfl_xor(n0, off)); n1 = fminf(n1, __shfl_xor(n1, off));
            x0 = fmaxf(x0, __shfl_xor(x0, off)); x1 = fmaxf(x1, __shfl_xor(x1, off));
        }
        int w = tid >> 6;
        if ((tid & 63) == 0) { mred[w][0] = n0; mred[w][1] = n1; mred[w][2] = x0; mred[w][3] = x1; }
        __syncthreads();
        if (tid == 0) {
            mmpart[c * 4 + 0] = fminf(fminf(mred[0][0], mred[1][0]), fminf(mred[2][0], mred[3][0]));
            mmpart[c * 4 + 1] = fminf(fminf(mred[0][1], mred[1][1]), fminf(mred[2][1], mred[3][1]));
            mmpart[c * 4 + 2] = fmaxf(fmaxf(mred[0][2], mred[1][2]), fmaxf(mred[2][2], mred[3][2]));
            mmpart[c * 4 + 3] = fmaxf(fmaxf(mred[0][3], mred[1][3]), fmaxf(mred[2][3], mred[3][3]));
        }
    }
}

__global__ __launch_bounds__(256) void tot_kernel(const unsigned* __restrict__ cntc,
                                                  unsigned* __restrict__ tot) {
    int v = blockIdx.x * 256 + threadIdx.x;
    int a = blockIdx.y;
    if (v >= NN) return;
    const unsigned* base = cntc + (size_t)a * NCHUNK * NN;
    unsigned s = 0;
    for (int c = 0; c < NCHUNK; c++) s += base[(size_t)c * NN + v];
    tot[a * NN + v] = s;
}

__global__ __launch_bounds__(1024) void scan_kernel(const unsigned* __restrict__ tot,
                                                    const float* __restrict__ mmpart,
                                                    unsigned* __restrict__ offp,
                                                    float* __restrict__ mmo) {
    __shared__ unsigned ts[1024];
    int t = threadIdx.x;
    if (t < 64) {
        float n0 = fminf(mmpart[4 * t + 0], mmpart[4 * (t + 64) + 0]);
        float n1 = fminf(mmpart[4 * t + 1], mmpart[4 * (t + 64) + 1]);
        float x0 = fmaxf(mmpart[4 * t + 2], mmpart[4 * (t + 64) + 2]);
        float x1 = fmaxf(mmpart[4 * t + 3], mmpart[4 * (t + 64) + 3]);
        #pragma unroll
        for (int off = 32; off >= 1; off >>= 1) {
            n0 = fminf(n0, __shfl_xor(n0, off)); n1 = fminf(n1, __shfl_xor(n1, off));
            x0 = fmaxf(x0, __shfl_xor(x0, off)); x1 = fmaxf(x1, __shfl_xor(x1, off));
        }
        if (t == 0) {
            mmo[0] = n0; mmo[1] = n1;
            mmo[2] = __fdividef(LOG2E, x0 - n0);   // L2E folded into the normalizer
            mmo[3] = __fdividef(LOG2E, x1 - n1);
        }
    }
    const int CH = 10;
    for (int a = 0; a < 2; a++) {
        const unsigned* c = tot + a * NN;
        unsigned* off = offp + a * (NN + 1);
        unsigned s = 0;
        int i0 = t * CH;
        #pragma unroll
        for (int k = 0; k < CH; k++) { int i = i0 + k; if (i < NN) s += c[i]; }
        ts[t] = s;
        __syncthreads();
        for (int d = 1; d < 1024; d <<= 1) {
            unsigned v = (t >= d) ? ts[t - d] : 0u;
            __syncthreads();
            ts[t] += v;
            __syncthreads();
        }
        unsigned run = ts[t] - s;
        #pragma unroll
        for (int k = 0; k < CH; k++) {
            int i = i0 + k;
            if (i < NN) { unsigned cv = c[i]; off[i] = run; run += cv; }
        }
        if (t == 1023) off[NN] = ts[1023];
        __syncthreads();
    }
}

__global__ __launch_bounds__(256) void base_kernel(unsigned* __restrict__ cntc,
                                                   const unsigned* __restrict__ offp) {
    int v = blockIdx.x * 256 + threadIdx.x;
    int a = blockIdx.y;
    if (v >= NN) return;
    unsigned run = offp[a * (NN + 1) + v];
    unsigned* base = cntc + (size_t)a * NCHUNK * NN;
    for (int c = 0; c < NCHUNK; c++) {
        unsigned cv = base[(size_t)c * NN + v];
        base[(size_t)c * NN + v] = run;
        run += cv;
    }
}

__global__ __launch_bounds__(256) void fill_kernel(const int* __restrict__ ei,
                                                   const unsigned* __restrict__ cntc,
                                                   unsigned* __restrict__ lst) {
    __shared__ unsigned cur[NN];
    const int c = blockIdx.x, a = blockIdx.y, tid = threadIdx.x;
    const unsigned* bs = cntc + ((size_t)a * NCHUNK + c) * NN;
    for (int i = tid; i < NN; i += 256) cur[i] = bs[i];
    __syncthreads();
    const int e0 = c * CHSZ;
    for (int k = tid; k < CHSZ; k += 256) {
        int e = e0 + k;
        int v = ei[(size_t)a * EE + e];
        unsigned p = atomicAdd(&cur[v], 1u);
        lst[(size_t)a * EE + p] = (unsigned)e;
    }
}

// ---------------- per-node precompute (pre1/pre2 prescaled; wind->sincos) ------
__global__ __launch_bounds__(256) void node_pre(const float* __restrict__ x,
                                                const float* __restrict__ W1,
                                                const float* __restrict__ wmin,
                                                const float* __restrict__ wmax,
                                                float* __restrict__ pre1,
                                                float* __restrict__ pre2,
                                                float* __restrict__ wind) {
    int id = blockIdx.x * 256 + threadIdx.x;
    if (id >= BB * NN) return;
    float xv[16];
    const float4* xp = (const float4*)(x + (size_t)id * 16);
    #pragma unroll
    for (int q = 0; q < 4; q++) {
        float4 v = xp[q];
        xv[4 * q + 0] = v.x; xv[4 * q + 1] = v.y;
        xv[4 * q + 2] = v.z; xv[4 * q + 3] = v.w;
    }
    float s1[32], s2[32];
    #pragma unroll
    for (int j = 0; j < 32; j++) { s1[j] = 0.f; s2[j] = 0.f; }
    #pragma unroll
    for (int r = 0; r < 16; r++) {
        float xr = xv[r];
        #pragma unroll
        for (int j = 0; j < 32; j++) {
            s1[j] = fmaf(xr, W1[r * 32 + j], s1[j]);
            s2[j] = fmaf(xr, W1[(16 + r) * 32 + j], s2[j]);
        }
    }
    float4* o1 = (float4*)(pre1 + (size_t)id * 32);
    float4* o2 = (float4*)(pre2 + (size_t)id * 32);
    #pragma unroll
    for (int q = 0; q < 8; q++) {
        o1[q] = make_float4(s1[4*q] * LOG2E, s1[4*q+1] * LOG2E, s1[4*q+2] * LOG2E, s1[4*q+3] * LOG2E);
        o2[q] = make_float4(s2[4*q] * LOG2E, s2[4*q+1] * LOG2E, s2[4*q+2] * LOG2E, s2[4*q+3] * LOG2E);
    }
    float sp = xv[14] * (wmax[0] - wmin[0]) + wmin[0];
    float dr = xv[15] * (wmax[1] - wmin[1]) + wmin[1];
    float sv, cv;
    sincosf(dr, &sv, &cv);
    ((float2*)wind)[id] = make_float2(sp * cv, sp * sv);
}

// ---------------- per-edge trig precompute: (cos(city)/dist, sin(city)/dist) ---
__global__ __launch_bounds__(256) void edge_pre(const float* __restrict__ ea,
                                                float* __restrict__ ecs) {
    int e = blockIdx.x * 256 + threadIdx.x;
    float2 av = ((const float2*)ea)[e];
    float sv, cv;
    sincosf(av.y, &sv, &cv);
    float rd = __fdividef(1.0f, av.x);
    ((float2*)ecs)[e] = make_float2(cv * rd, sv * rd);
}

// ---------------- phase B: edge MLP (dot2 f16 GEMMs) -> g[e][b][16] ------------
__global__ __launch_bounds__(256) void edge_mlp(const int* __restrict__ ei,
                                                const float* __restrict__ ea,
                                                const float* __restrict__ ecs,
                                                const float* __restrict__ pre1,
                                                const float* __restrict__ pre2,
                                                const float* __restrict__ wind,
                                                const float* __restrict__ mmo,
                                                const float* __restrict__ W1,
                                                const float* __restrict__ wsf,   // ws base (pack region)
                                                float* __restrict__ gbuf,
                                                int b0, int nb) {
    __shared__ float gs[256 * 17];

    const int tid = threadIdx.x;
    const int e = blockIdx.x * 256 + tid;
    const int brel = blockIdx.y;
    const int b = b0 + brel;

    const int src = ei[e];
    const int tgt = ei[EE + e];
    const float2 eav = ((const float2*)ea)[e];
    const float2 ec = ((const float2*)ecs)[e];
    const float2 wv = ((const float2*)wind)[(size_t)b * NN + src];

    // edge weight: relu(speed*cos(city-src)/dist) via precomputed sincos
    float ew = fmaxf(wv.x * ec.x + wv.y * ec.y, 0.f);
    // normalized edge attrs, prescaled by L2E (folded into mmo[2..3])
    float ean0 = (eav.x - mmo[0]) * mmo[2];
    float ean1 = (eav.y - mmo[1]) * mmo[3];

    const float* w1s = wsf + PK_W1S;
    const float* b1s = wsf + PK_B1S;
    const float* b2s = wsf + PK_B2S;
    const half2_t* W2p = (const half2_t*)(wsf + PK_W2P);
    const half2_t* Wnp = (const half2_t*)(wsf + PK_WNP);

    // layer 1: h = sigmoid(pre1+pre2+ean*W1r32/33+ew*W1r34+b1), all L2E-prescaled
    half2_t hp[16];
    const float4* p1 = (const float4*)(pre1 + ((size_t)b * NN + src) * 32);
    const float4* p2 = (const float4*)(pre2 + ((size_t)b * NN + tgt) * 32);
    #pragma unroll
    for (int q = 0; q < 8; q++) {
        float4 a = p1[q];
        float4 c = p2[q];
        float s0 = a.x + c.x, s1 = a.y + c.y, s2 = a.z + c.z, s3 = a.w + c.w;
        float h0, h1, h2, h3;
        {
            int j = 4 * q;
            h0 = sig2(s0 + ean0 * W1[32*32 + j+0] + ean1 * W1[33*32 + j+0] + ew * w1s[j+0] + b1s[j+0]);
            h1 = sig2(s1 + ean0 * W1[32*32 + j+1] + ean1 * W1[33*32 + j+1] + ew * w1s[j+1] + b1s[j+1]);
            h2 = sig2(s2 + ean0 * W1[32*32 + j+2] + ean1 * W1[33*32 + j+2] + ew * w1s[j+2] + b1s[j+2]);
            h3 = sig2(s3 + ean0 * W1[32*32 + j+3] + ean1 * W1[33*32 + j+3] + ew * w1s[j+3] + b1s[j+3]);
        }
        hp[2 * q]     = pkh2(h0, h1);
        hp[2 * q + 1] = pkh2(h2, h3);
    }

    // layer 2: ef = sigmoid(h @ W2 + b2) via dot2 (L2E prescaled)
    float ef[22];
    #pragma unroll
    for (int k = 0; k < 22; k++) ef[k] = b2s[k];
    #pragma unroll
    for (int j2 = 0; j2 < 16; j2++) {
        #pragma unroll
        for (int k = 0; k < 22; k++) ef[k] = fdot2(hp[j2], W2p[j2 * 22 + k], ef[k]);
    }
    half2_t efp[11];
    #pragma unroll
    for (int k2 = 0; k2 < 11; k2++) {
        float e0 = sig2(ef[2 * k2]);
        float e1 = sig2(ef[2 * k2 + 1]);
        efp[k2] = pkh2(e0, e1);
    }

    // output projection fold: g = ef @ Wn via dot2 (unscaled)
    float gg[16];
    #pragma unroll
    for (int i = 0; i < 16; i++) gg[i] = 0.f;
    #pragma unroll
    for (int k2 = 0; k2 < 11; k2++) {
        #pragma unroll
        for (int i = 0; i < 16; i++) gg[i] = fdot2(efp[k2], Wnp[k2 * 16 + i], gg[i]);
    }

    // transpose through LDS, coalesced stores
    #pragma unroll
    for (int i = 0; i < 16; i++) gs[tid * 17 + i] = gg[i];
    __syncthreads();

    const int c = tid & 15;
    const int base = tid >> 4;
    const size_t ebase = (size_t)blockIdx.x * 256;
    #pragma unroll
    for (int p = 0; p < 16; p++) {
        int s = base + p * 16;
        gbuf[((ebase + s) * (size_t)nb + brel) * 16 + c] = gs[s * 17 + c];
    }
}

// ---------------- phase C: gather + bn + sigmoid (r9-validated) ----------------
__global__ __launch_bounds__(256) void gather_kernel(const unsigned* __restrict__ offp,
                                                     const unsigned* __restrict__ lst,
                                                     const float* __restrict__ gbuf,
                                                     const float* __restrict__ bn,
                                                     float* __restrict__ out,
                                                     int b0, int nb, int npb, int lgper) {
    int tid = threadIdx.x;
    int n = blockIdx.x * npb + (tid >> lgper);
    int rem = tid & ((1 << lgper) - 1);
    int bi = rem >> 4;
    int c = rem & 15;

    unsigned s0 = offp[n], s1 = offp[n + 1];
    unsigned t0 = offp[NN + 1 + n], t1 = offp[NN + 1 + n + 1];

    float acc = 0.f;
    for (unsigned k = t0; k < t1; k++) {
        int e = (int)lst[EE + k];
        acc += gbuf[((size_t)e * nb + bi) * 16 + c];
    }
    for (unsigned k = s0; k < s1; k++) {
        int e = (int)lst[k];
        acc -= gbuf[((size_t)e * nb + bi) * 16 + c];
    }
    out[((size_t)(b0 + bi) * NN + n) * 16 + c] = sigmf(acc + bn[c]);
}

extern "C" void kernel_launch(void* const* d_in, const int* in_sizes, int n_in,
                              void* d_out, int out_size, void* d_ws, size_t ws_size,
                              hipStream_t stream) {
    const float* x    = (const float*)d_in[0];
    const int*   ei   = (const int*)d_in[1];
    const float* ea   = (const float*)d_in[2];
    const float* wmin = (const float*)d_in[3];
    const float* wmax = (const float*)d_in[4];
    const float* W1   = (const float*)d_in[5];
    const float* b1   = (const float*)d_in[6];
    const float* W2   = (const float*)d_in[7];
    const float* b2   = (const float*)d_in[8];
    const float* Wn   = (const float*)d_in[9];
    const float* bn   = (const float*)d_in[10];
    float* out = (float*)d_out;

    float* ws       = (float*)d_ws;
    float* mmo      = ws + OFF_MM;
    float* wind     = ws + OFF_WIND;
    float* ecs      = ws + OFF_ECS;
    float* pre1     = ws + OFF_PRE1;
    float* pre2     = ws + OFF_PRE2;
    unsigned* offp  = (unsigned*)(ws + OFF_OFFP);
    unsigned* tot   = (unsigned*)(ws + OFF_TOT);
    float* mmpart   = ws + OFF_MMP;
    unsigned* cntc  = (unsigned*)(ws + OFF_CNTC);
    unsigned* lst   = (unsigned*)(ws + OFF_LST);
    float* gbuf     = ws + OFF_G;

    int nb = 8;
    while (nb > 1 && ((size_t)OFF_G + (size_t)nb * EE * 16) * 4ull > ws_size) nb >>= 1;
    if (((size_t)OFF_G + (size_t)nb * EE * 16) * 4ull > ws_size) return;

    pack_kernel<<<1, 512, 0, stream>>>(W1, b1, W2, b2, Wn, ws);
    node_pre<<<(BB * NN + 255) / 256, 256, 0, stream>>>(x, W1, wmin, wmax, pre1, pre2, wind);
    edge_pre<<<EE / 256, 256, 0, stream>>>(ea, ecs);

    count_kernel<<<dim3(NCHUNK, 2), 256, 0, stream>>>(ei, ea, cntc, mmpart);
    tot_kernel<<<dim3((NN + 255) / 256, 2), 256, 0, stream>>>(cntc, tot);
    scan_kernel<<<1, 1024, 0, stream>>>(tot, mmpart, offp, mmo);
    base_kernel<<<dim3((NN + 255) / 256, 2), 256, 0, stream>>>(cntc, offp);
    fill_kernel<<<dim3(NCHUNK, 2), 256, 0, stream>>>(ei, cntc, lst);

    int lgnb = (nb == 8) ? 3 : (nb == 4) ? 2 : (nb == 2) ? 1 : 0;
    int per = 16 * nb;
    int npb = 256 / per;
    int lgper = 4 + lgnb;
    for (int bc = 0; bc < BB; bc += nb) {
        edge_mlp<<<dim3(EE / 256, nb), 256, 0, stream>>>(ei, ea, ecs, pre1, pre2, wind,
                                                         mmo, W1, ws, gbuf, bc, nb);
        gather_kernel<<<NN / npb, 256, 0, stream>>>(offp, lst, gbuf, bn, out,
                                                    bc, nb, npb, lgper);
    }
}